// Round 5
// baseline (381.340 us; speedup 1.0000x reference)
//
#include <hip/hip_runtime.h>

// YOLO-style loss: pred/target (bs, 7, 7, 30) fp32 -> scalar.
// S=7, B=2 boxes (5 ch each), C=20 classes. Memory-bound streaming reduction.
// Pass 1: block of 256 threads stages 256 cells (30 floats each) of both
// tensors into LDS with coalesced float4 loads; 1 thread = 1 cell computes
// the loss; wave-shuffle + LDS reduce -> one partial per block in d_ws.
// Pass 2: single block reduces partials -> out[0]. Deterministic, no atomics.
// Fallback (only if ws_size is too small for the partials): zero-init kernel
// + one atomicAdd per block directly into out[0].

#define CH 30
#define CPB 256  // cells per block
#define SDIV 7.0f

__device__ __forceinline__ float cell_loss_compute(const float* __restrict__ p,
                                                   const float* __restrict__ t)
{
    const float obj   = (t[4] > 0.0f) ? 1.0f : 0.0f;
    const float noobj = 1.0f - obj;

    // no-object confidence loss (conf channels 4 and 9; tgt conf == obj)
    const float d4 = p[4] - t[4];
    const float d9 = p[9] - t[9];
    const float l_noobj = d4 * d4 + d9 * d9;

    // class loss (channels 10..29)
    float l_class = 0.0f;
    #pragma unroll
    for (int c = 10; c < 30; ++c) {
        const float d = p[c] - t[c];
        l_class += d * d;
    }

    // target box 0 -> xyxy (matches reference op order)
    const float t_x0 = t[0] / SDIV - 0.5f * t[2];
    const float t_y0 = t[1] / SDIV - 0.5f * t[3];
    const float t_x1 = t[0] / SDIV + 0.5f * t[2];
    const float t_y1 = t[1] / SDIV + 0.5f * t[3];
    const float area_t = (t_x1 - t_x0) * (t_y1 - t_y0);

    float iou0 = 0.0f, iou1 = 0.0f;
    #pragma unroll
    for (int b = 0; b < 2; ++b) {
        const float* pb = p + 5 * b;
        const float p_x0 = pb[0] / SDIV - 0.5f * pb[2];
        const float p_y0 = pb[1] / SDIV - 0.5f * pb[3];
        const float p_x1 = pb[0] / SDIV + 0.5f * pb[2];
        const float p_y1 = pb[1] / SDIV + 0.5f * pb[3];
        const float ltx = fmaxf(p_x0, t_x0);
        const float lty = fmaxf(p_y0, t_y0);
        const float rbx = fminf(p_x1, t_x1);
        const float rby = fminf(p_y1, t_y1);
        const float w = fmaxf(rbx - ltx, 0.0f);
        const float h = fmaxf(rby - lty, 0.0f);
        const float inter  = w * h;
        const float area_p = (p_x1 - p_x0) * (p_y1 - p_y0);
        const float uni = fmaxf(area_p + area_t - inter, 1e-10f);
        const float iou = inter / uni;
        if (b == 0) iou0 = iou; else iou1 = iou;
    }

    // jnp.argmax picks first on ties -> box1 only if strictly greater
    const int bsel = (iou1 > iou0) ? 1 : 0;
    const float max_iou = bsel ? iou1 : iou0;
    const float* pr = p + 5 * bsel;
    const float* tr = t + 5 * bsel;

    const float dx = pr[0] - tr[0];
    const float dy = pr[1] - tr[1];
    const float l_xy = dx * dx + dy * dy;
    const float dw = sqrtf(pr[2]) - sqrtf(tr[2]);
    const float dh = sqrtf(pr[3]) - sqrtf(tr[3]);
    const float l_wh = dw * dw + dh * dh;
    const float dc = pr[4] - max_iou;
    const float l_obj = dc * dc;

    return obj * (5.0f * (l_xy + l_wh) + l_obj + l_class)
         + 0.5f * noobj * l_noobj;
}

template <bool USE_ATOMIC>
__global__ __launch_bounds__(256) void yolo_loss_pass1(
    const float* __restrict__ pred, const float* __restrict__ tgt,
    float* __restrict__ dst, long long n_cells, float scale)
{
    __shared__ float sp[CPB * CH];   // 30 KB
    __shared__ float st[CPB * CH];   // 30 KB
    __shared__ float wsums[4];

    const int tid = threadIdx.x;
    const long long cell0 = (long long)blockIdx.x * CPB;
    const long long base  = cell0 * CH;
    const long long total = n_cells * CH;
    const int TOT4 = CPB * CH / 4;               // 1920 float4s per tensor

    // ---- stage global -> LDS, coalesced float4 ----
    const float4* p4 = (const float4*)(pred + base);
    const float4* t4 = (const float4*)(tgt + base);
    float4* sp4 = (float4*)sp;
    float4* st4 = (float4*)st;
    long long rem4 = (total - base) / 4;
    int lim = (rem4 < 0) ? 0 : ((rem4 < TOT4) ? (int)rem4 : TOT4);
    for (int v = tid; v < lim; v += 256) {
        sp4[v] = p4[v];
        st4[v] = t4[v];
    }
    __syncthreads();

    // ---- per-cell loss ----
    float cell_loss = 0.0f;
    const long long cell = cell0 + tid;
    if (cell < n_cells)
        cell_loss = cell_loss_compute(sp + tid * CH, st + tid * CH);

    // ---- reduce: wave64 shuffle -> per-wave LDS -> per-block result ----
    float v = cell_loss;
    #pragma unroll
    for (int off = 32; off > 0; off >>= 1)
        v += __shfl_down(v, off, 64);

    const int wave = tid >> 6;
    const int lane = tid & 63;
    if (lane == 0) wsums[wave] = v;
    __syncthreads();
    if (tid == 0) {
        const float s = wsums[0] + wsums[1] + wsums[2] + wsums[3];
        if (USE_ATOMIC) atomicAdd(dst, s * scale);
        else            dst[blockIdx.x] = s;
    }
}

__global__ __launch_bounds__(256) void yolo_loss_pass2(
    const float* __restrict__ partials, float* __restrict__ out,
    int n_partials, float scale)
{
    __shared__ float wsums[4];
    const int tid = threadIdx.x;

    float v = 0.0f;
    for (int i = tid; i < n_partials; i += 256)
        v += partials[i];

    #pragma unroll
    for (int off = 32; off > 0; off >>= 1)
        v += __shfl_down(v, off, 64);

    const int wave = tid >> 6;
    const int lane = tid & 63;
    if (lane == 0) wsums[wave] = v;
    __syncthreads();
    if (tid == 0)
        out[0] = (wsums[0] + wsums[1] + wsums[2] + wsums[3]) * scale;
}

__global__ __launch_bounds__(64) void zero_out_kernel(float* out) {
    if (threadIdx.x == 0) out[0] = 0.0f;
}

extern "C" void kernel_launch(void* const* d_in, const int* in_sizes, int n_in,
                              void* d_out, int out_size, void* d_ws, size_t ws_size,
                              hipStream_t stream) {
    const float* pred = (const float*)d_in[0];
    const float* tgt  = (const float*)d_in[1];
    float* out = (float*)d_out;
    float* partials = (float*)d_ws;

    const long long total   = (long long)in_sizes[0];
    const long long n_cells = total / CH;          // bs*S*S
    const long long bs      = n_cells / 49;        // S*S = 49
    const float scale = 1.0f / (float)bs;

    const int grid = (int)((n_cells + CPB - 1) / CPB);

    if (ws_size >= (size_t)grid * sizeof(float)) {
        // deterministic two-pass path
        yolo_loss_pass1<false><<<grid, 256, 0, stream>>>(pred, tgt, partials,
                                                         n_cells, scale);
        yolo_loss_pass2<<<1, 256, 0, stream>>>(partials, out, grid, scale);
    } else {
        // fallback: zero-init + one atomic per block
        zero_out_kernel<<<1, 64, 0, stream>>>(out);
        yolo_loss_pass1<true><<<grid, 256, 0, stream>>>(pred, tgt, out,
                                                        n_cells, scale);
    }
}